// Round 6
// baseline (506.935 us; speedup 1.0000x reference)
//
#include <hip/hip_runtime.h>

// ---------------------------------------------------------------------------
// GCN pipeline. Round 6:
//  - CSR binned by (dst, src>>12): 13 src-ranges x 2MB of h -> per-XCD-L2-sized
//    working set; persistent gather loops ranges in outer loop (temporal align)
//  - GEMM: LDS-staged X tile (bf16x3 split at stage time), W pre-shuffled to
//    MFMA fragment order (coalesced 1KB B-loads)
//  - layer-2 gather fuses relu+pool (B never materialized), pool kernel gone
// ---------------------------------------------------------------------------

typedef short bf16x8 __attribute__((ext_vector_type(8)));
typedef float f32x4  __attribute__((ext_vector_type(4)));

#define RSHIFT 12               // src-range = 4096 nodes = 2 MB of features
#define NPW 13                  // nodes per wave in gather

__device__ inline unsigned short f2bf_rne(float f) {
    unsigned u = __float_as_uint(f);
    unsigned r = (u + 0x7fffu + ((u >> 16) & 1u)) >> 16;
    return (unsigned short)r;
}
__device__ inline float bf2f(unsigned short h) {
    return __uint_as_float(((unsigned)h) << 16);
}

// ---- CSR build over (dst, src-range) bins -------------------------------
__global__ void histbin_kernel(const int* __restrict__ src, const int* __restrict__ dst,
                               int* __restrict__ cnt2, int R, int E) {
    int e = blockIdx.x * blockDim.x + threadIdx.x;
    if (e < E) atomicAdd(&cnt2[dst[e] * R + (src[e] >> RSHIFT)], 1);
}

// generic per-block inclusive scan; block sums out
__global__ __launch_bounds__(256) void scan_blk(const int* __restrict__ in,
                                                int* __restrict__ incl,
                                                int* __restrict__ bsum, int n) {
    __shared__ int s[256];
    int tid = threadIdx.x;
    int i = blockIdx.x * 256 + tid;
    int v = (i < n) ? in[i] : 0;
    s[tid] = v;
    __syncthreads();
#pragma unroll
    for (int off = 1; off < 256; off <<= 1) {
        int t = (tid >= off) ? s[tid - off] : 0;
        __syncthreads();
        s[tid] += t;
        __syncthreads();
    }
    if (i < n) incl[i] = s[tid];
    if (tid == 255) bsum[blockIdx.x] = s[255];
}

// single-block inclusive scan (n<=256); also zeros pooled/cnt
__global__ __launch_bounds__(256) void scan_top(const int* __restrict__ in,
                                                int* __restrict__ incl, int n,
                                                float* __restrict__ pooled,
                                                float* __restrict__ cnt) {
    __shared__ int s[256];
    int tid = threadIdx.x;
    int v = (tid < n) ? in[tid] : 0;
    s[tid] = v;
    __syncthreads();
#pragma unroll
    for (int off = 1; off < 256; off <<= 1) {
        int t = (tid >= off) ? s[tid - off] : 0;
        __syncthreads();
        s[tid] += t;
        __syncthreads();
    }
    if (tid < n) incl[tid] = s[tid];
    for (int i = tid; i < 64 * 128; i += 256) pooled[i] = 0.f;
    if (tid < 64) cnt[tid] = 0.f;
}

// rowbin[i] = global exclusive prefix; cursor copy; rowbin[NB] = E
__global__ void finalize2_kernel(const int* __restrict__ cnt2, const int* __restrict__ tmpA,
                                 const int* __restrict__ S1i, const int* __restrict__ S2i,
                                 int* __restrict__ rowbin, int* __restrict__ cursor,
                                 int NB, int E) {
    int i = blockIdx.x * blockDim.x + threadIdx.x;
    if (i > NB) return;
    if (i == NB) { rowbin[NB] = E; return; }
    int b = i >> 8;
    int P = 0;
    if (b > 0) {
        int bb = b - 1;
        int B2 = bb >> 8;
        P = S1i[bb] + ((B2 > 0) ? S2i[B2 - 1] : 0);
    }
    int ex = tmpA[i] - cnt2[i] + P;
    rowbin[i] = ex;
    cursor[i] = ex;
}

__global__ void dinv_kernel(const int* __restrict__ rowbin, float* __restrict__ dinv,
                            int R, int N) {
    int n = blockIdx.x * blockDim.x + threadIdx.x;
    if (n < N) {
        int deg = rowbin[(n + 1) * R] - rowbin[n * R];
        dinv[n] = 1.0f / sqrtf((float)deg + 1.0f);
    }
}

__global__ void reorder_kernel(const int* __restrict__ src, const int* __restrict__ dst,
                               const float* __restrict__ dinv,
                               int* __restrict__ cursor, int2* __restrict__ em,
                               int R, int E) {
    int e = blockIdx.x * blockDim.x + threadIdx.x;
    if (e < E) {
        int s = src[e], d = dst[e];
        int pos = atomicAdd(&cursor[d * R + (s >> RSHIFT)], 1);
        float norm = dinv[s] * dinv[d];
        em[pos] = make_int2(s, __float_as_int(norm));
    }
}

// ---- weights: fp32 [k][n] -> bf16 hi/lo in MFMA fragment order ----------
// frag addr = ((ct*4+ks)*64 + (q*16+nn))*8 + j ; n=ct*16+nn, k=ks*32+q*8+j
__global__ __launch_bounds__(256) void wconv_kernel(const float* __restrict__ W1,
                                                    const float* __restrict__ W2,
                                                    unsigned short* __restrict__ W1h,
                                                    unsigned short* __restrict__ W1l,
                                                    unsigned short* __restrict__ W2h,
                                                    unsigned short* __restrict__ W2l) {
    int i = blockIdx.x * 256 + threadIdx.x;   // 0..32767
    const float* W = (i < 16384) ? W1 : W2;
    unsigned short* Wh = (i < 16384) ? W1h : W2h;
    unsigned short* Wl = (i < 16384) ? W1l : W2l;
    int ii = i & 16383;
    int k = ii >> 7, n = ii & 127;
    float v = W[ii];
    unsigned short h = f2bf_rne(v);
    float lo = v - bf2f(h);
    int ct = n >> 4, nn = n & 15, ks = k >> 5, q = (k >> 3) & 3, j = k & 7;
    int oidx = (((ct * 4 + ks) * 64) + (q * 16 + nn)) * 8 + j;
    Wh[oidx] = h;
    Wl[oidx] = f2bf_rne(lo);
}

// ---- GEMM: C[M,128] = act(X) @ W via bf16x3 MFMA ------------------------
template <bool RELU_IN>
__global__ __launch_bounds__(256) void gemm_mfma(const float* __restrict__ X,
                                                 const unsigned short* __restrict__ Wfh,
                                                 const unsigned short* __restrict__ Wfl,
                                                 float* __restrict__ OUT, int M) {
    __shared__ unsigned short Xh[64][136];   // 136: 16B-aligned rows, bank-spread
    __shared__ unsigned short Xl[64][136];
    int tid = threadIdx.x;
    int w = tid >> 6, l = tid & 63;
    int m0 = blockIdx.x * 64;

    // stage X tile (coalesced), split to bf16 hi/lo
#pragma unroll
    for (int it = 0; it < 8; it++) {
        int i = tid + it * 256;          // 0..2047
        int row = i >> 5, c4 = i & 31;
        int grow = m0 + row;
        float4 v = make_float4(0.f, 0.f, 0.f, 0.f);
        if (grow < M) v = *(const float4*)(X + (size_t)grow * 128 + c4 * 4);
        if (RELU_IN) {
            v.x = fmaxf(v.x, 0.f); v.y = fmaxf(v.y, 0.f);
            v.z = fmaxf(v.z, 0.f); v.w = fmaxf(v.w, 0.f);
        }
        float a[4] = {v.x, v.y, v.z, v.w};
        ushort4 hi, lo;
        unsigned short* hp = (unsigned short*)&hi;
        unsigned short* lp = (unsigned short*)&lo;
#pragma unroll
        for (int e = 0; e < 4; e++) {
            unsigned short h = f2bf_rne(a[e]);
            hp[e] = h;
            lp[e] = f2bf_rne(a[e] - bf2f(h));
        }
        *(ushort4*)&Xh[row][c4 * 4] = hi;
        *(ushort4*)&Xl[row][c4 * 4] = lo;
    }
    __syncthreads();

    int q = l >> 4, nn = l & 15;
    f32x4 acc[8];
#pragma unroll
    for (int ct = 0; ct < 8; ct++) acc[ct] = (f32x4){0.f, 0.f, 0.f, 0.f};

#pragma unroll
    for (int ks = 0; ks < 4; ks++) {
        bf16x8 ahi = *(const bf16x8*)&Xh[w * 16 + nn][ks * 32 + q * 8];
        bf16x8 alo = *(const bf16x8*)&Xl[w * 16 + nn][ks * 32 + q * 8];
#pragma unroll
        for (int ct = 0; ct < 8; ct++) {
            size_t fo = ((size_t)(ct * 4 + ks) * 64 + l) * 8;
            bf16x8 bhi = *(const bf16x8*)(Wfh + fo);
            bf16x8 blo = *(const bf16x8*)(Wfl + fo);
            acc[ct] = __builtin_amdgcn_mfma_f32_16x16x32_bf16(ahi, bhi, acc[ct], 0, 0, 0);
            acc[ct] = __builtin_amdgcn_mfma_f32_16x16x32_bf16(alo, bhi, acc[ct], 0, 0, 0);
            acc[ct] = __builtin_amdgcn_mfma_f32_16x16x32_bf16(ahi, blo, acc[ct], 0, 0, 0);
        }
    }
    // C/D: col = nn, row(in 16-tile) = q*4 + r
#pragma unroll
    for (int r = 0; r < 4; r++) {
        int row = m0 + w * 16 + q * 4 + r;
        if (row < M) {
#pragma unroll
            for (int ct = 0; ct < 8; ct++)
                OUT[(size_t)row * 128 + ct * 16 + nn] = acc[ct][r];
        }
    }
}

// ---- tiled gather: persistent, NPW nodes/wave, src-range outer loop -----
// POOL=false: B[n] = agg + self + bias.  POOL=true: relu(...) accumulated
// into pooled[batch[n]] (run-length, atomics at graph transitions only).
template <bool POOL>
__global__ __launch_bounds__(256) void gather_tiled(const float* __restrict__ h,
                                                    const float* __restrict__ dinv,
                                                    const float* __restrict__ bias,
                                                    const int* __restrict__ rowbin,
                                                    const long long* __restrict__ em,
                                                    int R, int N,
                                                    float* __restrict__ B,
                                                    const int* __restrict__ batch,
                                                    float* __restrict__ pooled,
                                                    float* __restrict__ cnt) {
    int wid = blockIdx.x * 4 + (threadIdx.x >> 6);
    int lane = threadIdx.x & 63;
    int n0 = wid * NPW;
    const float2* hp = (const float2*)h;

    float2 acc[NPW];
#pragma unroll
    for (int i = 0; i < NPW; i++) acc[i] = make_float2(0.f, 0.f);

    for (int r = 0; r < R; r++) {
#pragma unroll
        for (int i = 0; i < NPW; i++) {
            int n = n0 + i;
            if (n < N) {
                int beg = rowbin[n * R + r], end = rowbin[n * R + r + 1];
                for (int j = beg; j < end; j++) {
                    long long v = em[j];
                    int s = (int)v;
                    float nr = __int_as_float((int)(v >> 32));
                    float2 hs = hp[(size_t)s * 64 + lane];
                    acc[i].x = fmaf(hs.x, nr, acc[i].x);
                    acc[i].y = fmaf(hs.y, nr, acc[i].y);
                }
            }
        }
    }

    float bx = bias[lane * 2], by = bias[lane * 2 + 1];
    if (!POOL) {
#pragma unroll
        for (int i = 0; i < NPW; i++) {
            int n = n0 + i;
            if (n < N) {
                float di = dinv[n];
                float sw = di * di;
                float2 hv = hp[(size_t)n * 64 + lane];
                float2 o;
                o.x = fmaf(hv.x, sw, acc[i].x) + bx;
                o.y = fmaf(hv.y, sw, acc[i].y) + by;
                ((float2*)B)[(size_t)n * 64 + lane] = o;
            }
        }
    } else {
        float2 pacc = make_float2(0.f, 0.f);
        float pc = 0.f;
        int curg = -1;
#pragma unroll
        for (int i = 0; i < NPW; i++) {
            int n = n0 + i;
            if (n < N) {
                int g = batch[n];
                if (g != curg) {
                    if (curg >= 0) {
                        atomicAdd(&pooled[curg * 128 + lane * 2], pacc.x);
                        atomicAdd(&pooled[curg * 128 + lane * 2 + 1], pacc.y);
                        if (lane == 0) atomicAdd(&cnt[curg], pc);
                    }
                    curg = g; pacc = make_float2(0.f, 0.f); pc = 0.f;
                }
                float di = dinv[n];
                float sw = di * di;
                float2 hv = hp[(size_t)n * 64 + lane];
                float ox = fmaxf(fmaf(hv.x, sw, acc[i].x) + bx, 0.f);
                float oy = fmaxf(fmaf(hv.y, sw, acc[i].y) + by, 0.f);
                pacc.x += ox; pacc.y += oy; pc += 1.f;
            }
        }
        if (curg >= 0) {
            atomicAdd(&pooled[curg * 128 + lane * 2], pacc.x);
            atomicAdd(&pooled[curg * 128 + lane * 2 + 1], pacc.y);
            if (lane == 0) atomicAdd(&cnt[curg], pc);
        }
    }
}

// ---- head: one wave per graph ------------------------------------------
__global__ __launch_bounds__(64) void head_kernel(const float* __restrict__ pooled,
                                                  const float* __restrict__ cnt,
                                                  const float* __restrict__ Wfc1,
                                                  const float* __restrict__ bfc1,
                                                  const float* __restrict__ Wfc2,
                                                  const float* __restrict__ bfc2,
                                                  float* __restrict__ out) {
    __shared__ float mean[128];
    int g = blockIdx.x;
    int t = threadIdx.x;
    float inv = 1.0f / fmaxf(cnt[g], 1.0f);
    mean[t] = pooled[g * 128 + t] * inv;
    mean[t + 64] = pooled[g * 128 + t + 64] * inv;
    __syncthreads();
    float s = bfc1[t];
#pragma unroll 4
    for (int k = 0; k < 128; k++) s = fmaf(mean[k], Wfc1[k * 64 + t], s);
    float p = fmaxf(s, 0.f) * Wfc2[t];
#pragma unroll
    for (int o = 32; o > 0; o >>= 1) p += __shfl_down(p, o, 64);
    if (t == 0) out[g] = p + bfc2[0];
}

extern "C" void kernel_launch(void* const* d_in, const int* in_sizes, int n_in,
                              void* d_out, int out_size, void* d_ws, size_t ws_size,
                              hipStream_t stream) {
    const float* x    = (const float*)d_in[0];
    const int*   edge = (const int*)d_in[1];
    const int*   batch= (const int*)d_in[2];
    const float* W1   = (const float*)d_in[3];
    const float* b1   = (const float*)d_in[4];
    const float* W2   = (const float*)d_in[5];
    const float* b2   = (const float*)d_in[6];
    const float* Wfc1 = (const float*)d_in[7];
    const float* bfc1 = (const float*)d_in[8];
    const float* Wfc2 = (const float*)d_in[9];
    const float* bfc2 = (const float*)d_in[10];
    float* out = (float*)d_out;

    int N = in_sizes[0] / 128;
    int E = in_sizes[1] / 2;
    const int* src = edge;
    const int* dst = edge + E;

    int R = (N + (1 << RSHIFT) - 1) >> RSHIFT;      // src-ranges
    int NB = N * R;                                  // bins
    int nb1 = (NB + 255) / 256;
    int nb2 = (nb1 + 255) / 256;                     // <= 256 required

    char* ws = (char*)d_ws;
    size_t off = 0;
    auto alloc = [&](size_t bytes) { void* p = ws + off; off += (bytes + 255) & ~(size_t)255; return p; };
    float* A      = (float*)alloc((size_t)N * 128 * sizeof(float));
    float* B      = (float*)alloc((size_t)N * 128 * sizeof(float));
    float* dinv   = (float*)alloc((size_t)N * sizeof(float));
    int*   cnt2   = (int*)alloc((size_t)NB * sizeof(int));
    int*   tmpA   = (int*)alloc((size_t)NB * sizeof(int));
    int*   rowbin = (int*)alloc((size_t)(NB + 1) * sizeof(int));
    int*   cursor = (int*)alloc((size_t)NB * sizeof(int));
    int*   S1     = (int*)alloc((size_t)nb1 * sizeof(int));
    int*   S1i    = (int*)alloc((size_t)nb1 * sizeof(int));
    int*   S2     = (int*)alloc((size_t)nb2 * sizeof(int));
    int*   S2i    = (int*)alloc((size_t)nb2 * sizeof(int));
    int2*  em     = (int2*)alloc((size_t)E * sizeof(int2));
    float* pooled = (float*)alloc(64 * 128 * sizeof(float));
    float* cnt    = (float*)alloc(64 * sizeof(float));
    unsigned short* W1h = (unsigned short*)alloc(16384 * sizeof(short));
    unsigned short* W1l = (unsigned short*)alloc(16384 * sizeof(short));
    unsigned short* W2h = (unsigned short*)alloc(16384 * sizeof(short));
    unsigned short* W2l = (unsigned short*)alloc(16384 * sizeof(short));

    (void)hipMemsetAsync(cnt2, 0, (size_t)NB * sizeof(int), stream);

    // CSR(bin) build
    histbin_kernel<<<(E + 255) / 256, 256, 0, stream>>>(src, dst, cnt2, R, E);
    scan_blk<<<nb1, 256, 0, stream>>>(cnt2, tmpA, S1, NB);
    scan_blk<<<nb2, 256, 0, stream>>>(S1, S1i, S2, nb1);
    scan_top<<<1, 256, 0, stream>>>(S2, S2i, nb2, pooled, cnt);
    finalize2_kernel<<<(NB + 256) / 256, 256, 0, stream>>>(cnt2, tmpA, S1i, S2i, rowbin, cursor, NB, E);
    dinv_kernel<<<(N + 255) / 256, 256, 0, stream>>>(rowbin, dinv, R, N);
    reorder_kernel<<<(E + 255) / 256, 256, 0, stream>>>(src, dst, dinv, cursor, em, R, E);
    wconv_kernel<<<128, 256, 0, stream>>>(W1, W2, W1h, W1l, W2h, W2l);

    int gblocks = (N + 63) / 64;
    int tblocks = (N + 4 * NPW - 1) / (4 * NPW);    // persistent gather blocks

    // Layer 1
    gemm_mfma<false><<<gblocks, 256, 0, stream>>>(x, W1h, W1l, A, N);
    gather_tiled<false><<<tblocks, 256, 0, stream>>>(A, dinv, b1, rowbin,
        (const long long*)em, R, N, B, batch, pooled, cnt);

    // Layer 2 (relu fused into GEMM staging; gather fuses relu+pool)
    gemm_mfma<true><<<gblocks, 256, 0, stream>>>(B, W2h, W2l, A, N);
    gather_tiled<true><<<tblocks, 256, 0, stream>>>(A, dinv, b2, rowbin,
        (const long long*)em, R, N, nullptr, batch, pooled, cnt);

    // head (one wave per graph)
    head_kernel<<<64, 64, 0, stream>>>(pooled, cnt, Wfc1, bfc1, Wfc2, bfc2, out);
}